// Round 13
// baseline (79.972 us; speedup 1.0000x reference)
//
#include <hip/hip_runtime.h>

// AttentionLayer: N=2, L=2048, D_MODEL=512, H=8, d=64
#define NBATCH 2
#define SEQ    2048
#define DMODEL 512
#define NH     8
#define HDIM   64
#define SCALE  0.125f   // 1/sqrt(64)

// exp base-2: 0.125 * log2(e)
#define K2 0.1803368801111204f

#if __has_builtin(__builtin_amdgcn_exp2f)
#define EXP2(x) __builtin_amdgcn_exp2f(x)
#else
#define EXP2(x) __expf((x) * 0.6931471805599453f)
#endif

typedef __attribute__((ext_vector_type(8)))  short bf16x8;   // MFMA A/B frag
typedef __attribute__((ext_vector_type(4)))  float f32x4;    // 16x16 C/D frag
typedef __attribute__((ext_vector_type(16))) float f32x16;   // 32x32 C/D frag

// fp32 -> bf16 round-to-nearest-even.
__device__ __forceinline__ unsigned short f2bf(float f) {
    union { float f; unsigned u; } v; v.f = f;
    unsigned r = v.u + 0x7FFFu + ((v.u >> 16) & 1u);
    return (unsigned short)(r >> 16);
}

__device__ __forceinline__ void pack4(unsigned short* dst, float4 v) {
    unsigned long long pk = (unsigned long long)f2bf(v.x)
        | ((unsigned long long)f2bf(v.y) << 16)
        | ((unsigned long long)f2bf(v.z) << 32)
        | ((unsigned long long)f2bf(v.w) << 48);
    __builtin_memcpy(dst, &pk, 8);   // alias-safe 8B LDS/global store
}

__device__ __forceinline__ bf16x8 pack8(float4 a, float4 b) {
    bf16x8 r;
    r[0]=(short)f2bf(a.x); r[1]=(short)f2bf(a.y); r[2]=(short)f2bf(a.z); r[3]=(short)f2bf(a.w);
    r[4]=(short)f2bf(b.x); r[5]=(short)f2bf(b.y); r[6]=(short)f2bf(b.z); r[7]=(short)f2bf(b.w);
    return r;
}

// pack two f32 -> one dword of 2 bf16 (RNE), low word = s0. REGISTER-ONLY use.
__device__ __forceinline__ unsigned cvt_pk_bf16(float s0, float s1) {
    unsigned d;
    asm("v_cvt_pk_bf16_f32 %0, %1, %2" : "=v"(d) : "v"(s0), "v"(s1));
    return d;
}

// async 16B global->LDS DMA; lds dest is wave-uniform base + lane*16;
// swizzling is done on the GLOBAL source address (rule #21).
__device__ __forceinline__ void gld_lds16(const unsigned short* g, unsigned short* l) {
    __builtin_amdgcn_global_load_lds(
        (const __attribute__((address_space(1))) unsigned int*)(const void*)g,
        (__attribute__((address_space(3))) unsigned int*)(void*)l, 16, 0, 0);
}

// ---------------------------------------------------------------------------
// Prep: xb = bf16(x) row-major [n][l][512]; xt = bf16(x) transposed per head
// [n][h][64][2048]. Grid: n x h x (SEQ/64) = 512 blocks. Reads x once.
// ---------------------------------------------------------------------------
__global__ __launch_bounds__(256) void prep_kernel(const float* __restrict__ x,
                                                   unsigned short* __restrict__ xb,
                                                   unsigned short* __restrict__ xt) {
    __shared__ unsigned short Tb[64][72];   // 9216 B, padded
    const int bid = blockIdx.x;
    const int n = bid >> 8, h = (bid >> 5) & 7, st = bid & 31;
    const int s0 = st * 64;
    const int t = threadIdx.x;
    {
        const int s = t >> 2, d0 = (t & 3) * 16;
        const float* xp = x + ((size_t)(n*SEQ + s0 + s))*DMODEL + h*HDIM + d0;
        #pragma unroll
        for (int i = 0; i < 4; ++i) pack4(&Tb[s][d0 + 4*i], *(const float4*)(xp + 4*i));
    }
    __syncthreads();
    {   // xb slice write (row-major, 32B/thread)
        const int s = t >> 2, d0 = (t & 3) * 16;
        unsigned short* bp = xb + ((size_t)(n*SEQ + s0 + s))*DMODEL + h*HDIM + d0;
        *(bf16x8*)bp       = *(const bf16x8*)&Tb[s][d0];
        *(bf16x8*)(bp + 8) = *(const bf16x8*)&Tb[s][d0 + 8];
    }
    {   // xt slice write (transposed, 32B/thread)
        const int d = t >> 2, c0 = (t & 3) * 16;
        bf16x8 v0, v1;
        #pragma unroll
        for (int j = 0; j < 8; ++j) {
            v0[j] = (short)Tb[c0 + j][d];
            v1[j] = (short)Tb[c0 + 8 + j][d];
        }
        unsigned short* tp = xt + ((size_t)((n*NH + h)*HDIM + d))*SEQ + s0 + c0;
        *(bf16x8*)tp       = v0;
        *(bf16x8*)(tp + 8) = v1;
    }
}

// ---------------------------------------------------------------------------
// Kernel A (v5): 32x32x16 MFMA, in-register P, LDS-traffic-minimized.
// (unchanged from round 12 — passed at absmax 0.03125)
// ---------------------------------------------------------------------------
__global__ __launch_bounds__(256, 4) void out_kernel5(const unsigned short* __restrict__ xb,
                                                      const unsigned short* __restrict__ xt,
                                                      float* __restrict__ out,
                                                      float* __restrict__ rho,
                                                      float* __restrict__ part,
                                                      int split) {
    __shared__ unsigned short Kb[2][64*64];   // 16384 B, swizzled linear
    __shared__ unsigned short Vt[2][64*64];   // 16384 B, swizzled linear

    const int i   = blockIdx.x;
    const int cps = gridDim.x >> 3;            // 64 (512) or 128 (1024)
    const int bid = (i & 7) * cps + (i >> 3);  // bijective XCD-chunked swizzle
    int n, h, lt, ss;
    if (split) { n = bid >> 9; h = (bid >> 6) & 7; lt = (bid >> 1) & 31; ss = bid & 1; }
    else       { n = bid >> 8; h = (bid >> 5) & 7; lt = bid & 31;        ss = 0;       }
    const int l0 = lt * 64;
    const int sbase = ss << 10;
    const int nch = split ? 16 : 32;

    const int tid = threadIdx.x;
    const int wv = tid >> 6, lane = tid & 63;
    const int lrow = lane & 31;               // 32-wide lane row/col index
    const int hi = lane >> 5;                 // lane half
    const int qh = wv & 1, sh = wv >> 1;      // wave roles

    // Q frags in registers: B-frag (col=lane&31=q, k=(lane>>5)*8+j), 4 k-steps
    const unsigned short* qg = xb + ((size_t)(n*SEQ + l0 + qh*32 + lrow))*DMODEL + h*HDIM;
    bf16x8 qf[4];
    #pragma unroll
    for (int kst = 0; kst < 4; ++kst)
        qf[kst] = *(const bf16x8*)(qg + kst*16 + hi*8);

    const int srow8  = wv*8 + (lane >> 3);    // staging row (all 4 waves)
    const int schunk = lane & 7;
    const unsigned short* kbase = xb + (size_t)(n*SEQ)*DMODEL + h*HDIM;
    const unsigned short* vbase = xt + ((size_t)(n*NH + h)*HDIM)*SEQ;

    auto stage = [&](int buf, int s0) {
        #pragma unroll
        for (int it = 0; it < 2; ++it) {
            const int row = it*32 + srow8;
            const int gc  = schunk ^ (row & 7);
            gld_lds16(kbase + (size_t)(s0 + row)*DMODEL + gc*8,
                      &Kb[buf][it*2048 + wv*512]);
        }
        #pragma unroll
        for (int it = 0; it < 2; ++it) {
            const int d  = it*32 + srow8;
            const int gc = schunk ^ (d & 7);
            gld_lds16(vbase + (size_t)d*SEQ + s0 + gc*8,
                      &Vt[buf][it*2048 + wv*512]);
        }
    };

    f32x16 ovA = {0.f}, ovB = {0.f};   // O partial: d-tile 0 / 1, col q
    #pragma unroll
    for (int r = 0; r < 16; ++r) { ovA[r] = 0.f; ovB[r] = 0.f; }
    float rs = 0.f;                    // row-sum partial (this lane's e's)

    stage(0, sbase);
    __syncthreads();
    int cur = 0;

    for (int c = 0; c < nch; ++c) {
        if (c < nch - 1) stage(cur ^ 1, sbase + (c + 1) * 64);   // prefetch

        // ---- QK^T (swapped): D[s][q], s-tile = sh half of chunk ----
        f32x16 acc;
        #pragma unroll
        for (int r = 0; r < 16; ++r) acc[r] = 0.f;
        #pragma unroll
        for (int kst = 0; kst < 4; ++kst) {
            const int g = ((kst*2 + hi) ^ (lrow & 7)) << 3;   // inverse swizzle
            const bf16x8 kf = *(const bf16x8*)&Kb[cur][(sh*32 + lrow)*64 + g];
            acc = __builtin_amdgcn_mfma_f32_32x32x16_bf16(kf, qf[kst], acc, 0, 0, 0);
        }
        // ---- exp (in place) + row-sum ----
        #pragma unroll
        for (int r = 0; r < 16; ++r) {
            acc[r] = EXP2(acc[r] * K2);
            rs += acc[r];
        }
        // ---- PV: two 16-s steps; P assembled in-register ----
        #pragma unroll
        for (int p = 0; p < 2; ++p) {
            const unsigned g0 = cvt_pk_bf16(acc[8*p+0], acc[8*p+1]);
            const unsigned g1 = cvt_pk_bf16(acc[8*p+2], acc[8*p+3]);
            const unsigned g2 = cvt_pk_bf16(acc[8*p+4], acc[8*p+5]);
            const unsigned g3 = cvt_pk_bf16(acc[8*p+6], acc[8*p+7]);
            const unsigned b0 = hi ? g0 : g2;
            const unsigned b1 = hi ? g1 : g3;
            const unsigned r0 = (unsigned)__shfl_xor((int)b0, 32);
            const unsigned r1 = (unsigned)__shfl_xor((int)b1, 32);
            union { unsigned u[4]; bf16x8 h8; } pf;
            pf.u[0] = hi ? r0 : g0;
            pf.u[1] = hi ? r1 : g1;
            pf.u[2] = hi ? g2 : r0;
            pf.u[3] = hi ? g3 : r1;
            const int gv = ((sh*4 + p*2 + hi) ^ (lrow & 7)) << 3;
            const bf16x8 v0 = *(const bf16x8*)&Vt[cur][( 0 + lrow)*64 + gv];
            const bf16x8 v1 = *(const bf16x8*)&Vt[cur][(32 + lrow)*64 + gv];
            ovA = __builtin_amdgcn_mfma_f32_32x32x16_bf16(v0, pf.h8, ovA, 0, 0, 0);
            ovB = __builtin_amdgcn_mfma_f32_32x32x16_bf16(v1, pf.h8, ovB, 0, 0, 0);
        }
        __syncthreads();   // next buffer staged + all reads of cur done
        cur ^= 1;
    }

    // ---- cross-sh reduction (O and rs) via reused LDS ----
    rs += __shfl_xor(rs, 32);                  // sum over lane halves (same q)
    float* red = (float*)&Vt[0][0];            // 16 KB: [qh][q32][d]
    float* rsr = (float*)&Kb[0][0];            // 256 B: [qh*32+q32]
    if (sh == 1) {
        #pragma unroll
        for (int g = 0; g < 4; ++g) {
            float4 a = { ovA[4*g+0], ovA[4*g+1], ovA[4*g+2], ovA[4*g+3] };
            float4 b = { ovB[4*g+0], ovB[4*g+1], ovB[4*g+2], ovB[4*g+3] };
            *(float4*)&red[qh*2048 + lrow*64 +  0 + g*8 + 4*hi] = a;
            *(float4*)&red[qh*2048 + lrow*64 + 32 + g*8 + 4*hi] = b;
        }
        if (hi == 0) rsr[qh*32 + lrow] = rs;
    }
    __syncthreads();
    if (sh == 0) {
        const float rs_tot = rs + rsr[qh*32 + lrow];
        #pragma unroll
        for (int g = 0; g < 4; ++g) {
            float4 a = *(const float4*)&red[qh*2048 + lrow*64 +  0 + g*8 + 4*hi];
            float4 b = *(const float4*)&red[qh*2048 + lrow*64 + 32 + g*8 + 4*hi];
            ovA[4*g+0]+=a.x; ovA[4*g+1]+=a.y; ovA[4*g+2]+=a.z; ovA[4*g+3]+=a.w;
            ovB[4*g+0]+=b.x; ovB[4*g+1]+=b.y; ovB[4*g+2]+=b.z; ovB[4*g+3]+=b.w;
        }
        const int qloc = qh*32 + lrow;
        if (split) {
            float* pp = part + ((size_t)(((n*NH + h)*32 + lt)*2 + ss))*4160;
            #pragma unroll
            for (int g = 0; g < 4; ++g) {
                float4 a = { ovA[4*g+0], ovA[4*g+1], ovA[4*g+2], ovA[4*g+3] };
                float4 b = { ovB[4*g+0], ovB[4*g+1], ovB[4*g+2], ovB[4*g+3] };
                *(float4*)&pp[qloc*64 +  0 + g*8 + 4*hi] = a;
                *(float4*)&pp[qloc*64 + 32 + g*8 + 4*hi] = b;
            }
            if (hi == 0) pp[4096 + qloc] = rs_tot;
        } else {
            const float iv = 1.f / rs_tot;
            float* op = out + ((size_t)(n*SEQ + l0 + qloc))*DMODEL + h*HDIM;
            #pragma unroll
            for (int g = 0; g < 4; ++g) {
                float4 a = { ovA[4*g+0]*iv, ovA[4*g+1]*iv, ovA[4*g+2]*iv, ovA[4*g+3]*iv };
                float4 b = { ovB[4*g+0]*iv, ovB[4*g+1]*iv, ovB[4*g+2]*iv, ovB[4*g+3]*iv };
                *(float4*)&op[ 0 + g*8 + 4*hi] = a;
                *(float4*)&op[32 + g*8 + 4*hi] = b;
            }
            if (hi == 0) rho[(size_t)(n*NH + h)*SEQ + l0 + qloc] = rs_tot;
        }
    }
}

// ---------------------------------------------------------------------------
// Kernel B (v5): attn head-mean + absorbed combine.
// - Q frags loaded DIRECTLY from global into regs per head (L2-resident) ->
//   no Q staging; K-only LDS double-buffer: 18.4 KB -> 8 blocks/CU
//   (grid 2048 = exactly one full resident round at 32 waves/CU).
// - split path (part != null): invb computed from part sums (rho array dead);
//   blocks with st<8 ALSO write out[] for (n, h=st, lt) (old combine_kernel).
// - non-split: reads rho, no combine.
// ---------------------------------------------------------------------------
__global__ __launch_bounds__(256) void mean_kernel5(const unsigned short* __restrict__ xb,
                                                    const float* __restrict__ rho,
                                                    const float* __restrict__ part,
                                                    float* __restrict__ out,
                                                    float* __restrict__ attn) {
    __shared__ unsigned short Kb[2][64*64];   // 2 x 8 KB, swizzled linear
    __shared__ float invb[NH][64];            // 2 KB

    const int i   = blockIdx.x;
    const int bid = (i & 7) * 256 + (i >> 3);  // bijective (2048 = 8*256)
    const int n = bid >> 10, lt = (bid >> 5) & 31, st = bid & 31;
    const int l0 = lt * 64, s0 = st * 64;
    const int tid = threadIdx.x;
    const int wv = tid >> 6, lane = tid & 63;
    const int lr = lane & 15, lg = lane >> 4;

    const int srow8  = wv*8 + (lane >> 3);
    const int schunk = lane & 7;

    auto stage = [&](int buf, int h) {
        #pragma unroll
        for (int it = 0; it < 2; ++it) {   // K tile: 64 rows x 128B
            const int row = it*32 + srow8;
            const int gc  = schunk ^ (row & 7);
            gld_lds16(xb + ((size_t)(n*SEQ + s0 + row))*DMODEL + h*HDIM + gc*8,
                      &Kb[buf][it*2048 + wv*512]);
        }
    };

    stage(0, 0);                              // issue first K DMA ASAP

    // absorbed combine: blocks st<8 write out[] for (n, h=st, lt)
    if (part != nullptr && st < NH) {
        const int hC = st;
        const float* p0 = part + ((size_t)(((n*NH + hC)*32 + lt)*2))*4160;
        const float* p1 = p0 + 4160;
        const int q = tid >> 2, dg = (tid & 3) * 16;
        const float rsT = p0[4096 + q] + p1[4096 + q];
        const float iv = 1.f / rsT;
        float* op = out + ((size_t)(n*SEQ + l0 + q))*DMODEL + hC*HDIM + dg;
        #pragma unroll
        for (int k = 0; k < 4; ++k) {
            float4 a = *(const float4*)&p0[q*64 + dg + 4*k];
            float4 b = *(const float4*)&p1[q*64 + dg + 4*k];
            float4 o = { (a.x+b.x)*iv, (a.y+b.y)*iv, (a.z+b.z)*iv, (a.w+b.w)*iv };
            *(float4*)&op[4*k] = o;
        }
    }

    // invb: 0.125/rho per (head, row); rho from part sums in split path
    for (int j = tid; j < NH*64; j += 256) {
        const int hh = j >> 6, row = j & 63;
        float rv;
        if (part != nullptr) {
            const float* pb_ = part + ((size_t)(((n*NH + hh)*32 + lt)*2))*4160 + 4096;
            rv = pb_[row] + pb_[4160 + row];
        } else {
            rv = rho[(size_t)(n*NH + hh)*SEQ + l0 + row];
        }
        invb[hh][row] = 0.125f / rv;
    }

    float mean[4][4];
    #pragma unroll
    for (int ct = 0; ct < 4; ++ct)
        #pragma unroll
        for (int r = 0; r < 4; ++r) mean[ct][r] = 0.f;

    __syncthreads();                       // covers invb writes + K DMA drain
    int cur = 0;

    const int qrow = wv*16 + lr;
    const unsigned short* qg = xb + ((size_t)(n*SEQ + l0 + qrow))*DMODEL;

    for (int h = 0; h < NH; ++h) {
        if (h < NH-1) stage(cur ^ 1, h + 1);

        // Q frags straight from global (B-frag: col=lr, k=lg*8+j), L2-hot
        const bf16x8 a0 = *(const bf16x8*)(qg + h*HDIM + lg*8);
        const bf16x8 a1 = *(const bf16x8*)(qg + h*HDIM + 32 + lg*8);
        const float logiv = __log2f(invb[h][qrow]);
        const int c0 = (lg ^ (lr & 7)) << 3;
        #pragma unroll
        for (int ct = 0; ct < 4; ++ct) {
            const unsigned short* kr = &Kb[cur][(ct*16 + lr)*64];
            bf16x8 b0 = *(const bf16x8*)&kr[c0];
            bf16x8 b1 = *(const bf16x8*)&kr[c0 ^ 32];
            f32x4 acc = {0.f,0.f,0.f,0.f};
            acc = __builtin_amdgcn_mfma_f32_16x16x32_bf16(b0, a0, acc, 0,0,0);
            acc = __builtin_amdgcn_mfma_f32_16x16x32_bf16(b1, a1, acc, 0,0,0);
            #pragma unroll
            for (int r = 0; r < 4; ++r)
                mean[ct][r] += EXP2(fmaf(acc[r], K2, logiv));
        }
        __syncthreads();
        cur ^= 1;
    }

    // epilogue: per lane 4 consecutive s per ct -> float4 stores
    const int arow = n*SEQ + l0 + qrow;
    #pragma unroll
    for (int ct = 0; ct < 4; ++ct) {
        float4 v = { mean[ct][0], mean[ct][1], mean[ct][2], mean[ct][3] };
        *(float4*)&attn[(size_t)arow*SEQ + s0 + ct*16 + lg*4] = v;
    }
}

// ============================ fallback path ================================
// (round-3 kernels, used only if ws_size can't hold xb+xt; known-correct)
__global__ __launch_bounds__(256) void fb_out_kernel(const float* __restrict__ x,
                                                     float* __restrict__ out,
                                                     float* __restrict__ rho) {
    __shared__ unsigned short Kbuf[128][72];
    __shared__ unsigned short vT[64][136];
    __shared__ unsigned short pbuf[64][136];
    const int bid = blockIdx.x;
    const int n  = bid >> 8, h = (bid >> 5) & 7, lt = bid & 31;
    const int l0 = lt * 64;
    const int tid = threadIdx.x;
    const int wv  = tid >> 6, lane = tid & 63;
    const int lr  = lane & 15, lg = lane >> 4;
    const float* qp = x + ((size_t)(n*SEQ + l0 + wv*16 + lr))*DMODEL + h*HDIM + lg*8;
    const bf16x8 a0 = pack8(*(const float4*)qp,      *(const float4*)(qp+4));
    const bf16x8 a1 = pack8(*(const float4*)(qp+32), *(const float4*)(qp+36));
    f32x4 ov0 = {0.f,0.f,0.f,0.f}, ov1 = {0.f,0.f,0.f,0.f};
    f32x4 ov2 = {0.f,0.f,0.f,0.f}, ov3 = {0.f,0.f,0.f,0.f};
    float rs[4] = {0.f,0.f,0.f,0.f};
    for (int s0 = 0; s0 < SEQ; s0 += 128) {
        __syncthreads();
        {
            const int srow = tid >> 1, dbase = (tid & 1) * 32;
            const float* kp = x + ((size_t)(n*SEQ + s0 + srow))*DMODEL + h*HDIM + dbase;
            #pragma unroll
            for (int i = 0; i < 8; ++i) {
                float4 v = *(const float4*)(kp + 4*i);
                pack4(&Kbuf[srow][dbase + 4*i], v);
                const int d = dbase + 4*i;
                vT[d+0][srow] = f2bf(v.x); vT[d+1][srow] = f2bf(v.y);
                vT[d+2][srow] = f2bf(v.z); vT[d+3][srow] = f2bf(v.w);
            }
        }
        __syncthreads();
        #pragma unroll
        for (int ct = 0; ct < 8; ++ct) {
            const unsigned short* bp = &Kbuf[ct*16 + lr][lg*8];
            bf16x8 b0 = *(const bf16x8*)bp;
            bf16x8 b1 = *(const bf16x8*)(bp + 32);
            f32x4 acc = {0.f,0.f,0.f,0.f};
            acc = __builtin_amdgcn_mfma_f32_16x16x32_bf16(a0, b0, acc, 0,0,0);
            acc = __builtin_amdgcn_mfma_f32_16x16x32_bf16(a1, b1, acc, 0,0,0);
            #pragma unroll
            for (int r = 0; r < 4; ++r) {
                const float e = __expf(acc[r] * SCALE);
                rs[r] += e;
                pbuf[wv*16 + lg*4 + r][ct*16 + lr] = f2bf(e);
            }
        }
        __syncthreads();
        #pragma unroll
        for (int ks = 0; ks < 4; ++ks) {
            bf16x8 pa = *(const bf16x8*)&pbuf[wv*16 + lr][ks*32 + lg*8];
            bf16x8 v0 = *(const bf16x8*)&vT[ 0 + lr][ks*32 + lg*8];
            bf16x8 v1 = *(const bf16x8*)&vT[16 + lr][ks*32 + lg*8];
            bf16x8 v2 = *(const bf16x8*)&vT[32 + lr][ks*32 + lg*8];
            bf16x8 v3 = *(const bf16x8*)&vT[48 + lr][ks*32 + lg*8];
            ov0 = __builtin_amdgcn_mfma_f32_16x16x32_bf16(pa, v0, ov0, 0,0,0);
            ov1 = __builtin_amdgcn_mfma_f32_16x16x32_bf16(pa, v1, ov1, 0,0,0);
            ov2 = __builtin_amdgcn_mfma_f32_16x16x32_bf16(pa, v2, ov2, 0,0,0);
            ov3 = __builtin_amdgcn_mfma_f32_16x16x32_bf16(pa, v3, ov3, 0,0,0);
        }
    }
    #pragma unroll
    for (int r = 0; r < 4; ++r) {
        float s = rs[r];
        s += __shfl_xor(s, 1, 16); s += __shfl_xor(s, 2, 16);
        s += __shfl_xor(s, 4, 16); s += __shfl_xor(s, 8, 16);
        rs[r] = s;
    }
    const int row0 = l0 + wv*16 + lg*4;
    if (lr == 0) {
        #pragma unroll
        for (int r = 0; r < 4; ++r)
            rho[(size_t)(n*NH + h)*SEQ + row0 + r] = rs[r];
    }
    #pragma unroll
    for (int r = 0; r < 4; ++r) {
        const float iv = 1.f / rs[r];
        float* op = out + ((size_t)(n*SEQ + row0 + r))*DMODEL + h*HDIM + lr;
        op[0] = ov0[r]*iv; op[16] = ov1[r]*iv; op[32] = ov2[r]*iv; op[48] = ov3[r]*iv;
    }
}

__global__ __launch_bounds__(256) void fb_mean_kernel(const float* __restrict__ x,
                                                      const float* __restrict__ rho,
                                                      float* __restrict__ attn) {
    __shared__ unsigned short Qb[64][72];
    __shared__ unsigned short Kb[128][72];
    __shared__ float          invb[64];
    const int bid = blockIdx.x;
    const int n  = bid >> 9, lt = (bid >> 4) & 31, st = bid & 15;
    const int l0 = lt * 64, s0 = st * 128;
    const int tid = threadIdx.x;
    const int wv  = tid >> 6, lane = tid & 63;
    const int lr  = lane & 15, lg = lane >> 4;
    float mean[8][4];
    #pragma unroll
    for (int ct = 0; ct < 8; ++ct)
        #pragma unroll
        for (int r = 0; r < 4; ++r) mean[ct][r] = 0.f;
    for (int h = 0; h < NH; ++h) {
        __syncthreads();
        {
            const int qrow = tid >> 2, qd = (tid & 3) * 16;
            const float* qp = x + ((size_t)(n*SEQ + l0 + qrow))*DMODEL + h*HDIM + qd;
            #pragma unroll
            for (int i = 0; i < 4; ++i)
                pack4(&Qb[qrow][qd + 4*i], *(const float4*)(qp + 4*i));
        }
        {
            const int srow = tid >> 1, dbase = (tid & 1) * 32;
            const float* kp = x + ((size_t)(n*SEQ + s0 + srow))*DMODEL + h*HDIM + dbase;
            #pragma unroll
            for (int i = 0; i < 8; ++i)
                pack4(&Kb[srow][dbase + 4*i], *(const float4*)(kp + 4*i));
        }
        if (tid < 64)
            invb[tid] = 0.125f / rho[(size_t)(n*NH + h)*SEQ + l0 + tid];
        __syncthreads();
        const unsigned short* ap = &Qb[wv*16 + lr][lg*8];
        const bf16x8 a0 = *(const bf16x8*)ap;
        const bf16x8 a1 = *(const bf16x8*)(ap + 32);
        #pragma unroll
        for (int ct = 0; ct < 8; ++ct) {
            const unsigned short* bp = &Kb[ct*16 + lr][lg*8];
            bf16x8 b0 = *(const bf16x8*)bp;
            bf16x8 b1 = *(const bf16x8*)(bp + 32);
            f32x4 acc = {0.f,0.f,0.f,0.f};
            acc = __builtin_amdgcn_mfma_f32_16x16x32_bf16(a0, b0, acc, 0,0,0);
            acc = __builtin_amdgcn_mfma_f32_16x16x32_bf16(a1, b1, acc, 0,0,0);
            #pragma unroll
            for (int r = 0; r < 4; ++r)
                mean[ct][r] += __expf(acc[r] * SCALE) * invb[wv*16 + lg*4 + r];
        }
    }
    #pragma unroll
    for (int ct = 0; ct < 8; ++ct)
        #pragma unroll
        for (int r = 0; r < 4; ++r)
            attn[((size_t)(n*SEQ + l0 + wv*16 + lg*4 + r))*SEQ + s0 + ct*16 + lr]
                = mean[ct][r];
}

extern "C" void kernel_launch(void* const* d_in, const int* in_sizes, int n_in,
                              void* d_out, int out_size, void* d_ws, size_t ws_size,
                              hipStream_t stream) {
    (void)in_sizes; (void)n_in; (void)out_size;
    const float* x = (const float*)d_in[0];
    float* out  = (float*)d_out;                          // [2][2048][512]
    float* attn = out + (size_t)NBATCH*SEQ*DMODEL;        // [2][2048][2048]
    float* rho  = (float*)d_ws;                           // 128 KiB

    const size_t XB_OFF   = 131072;                       // 4 MiB bf16 copy
    const size_t XT_OFF   = XB_OFF + 4194304;             // 4 MiB bf16 transpose
    const size_t NEED1    = XT_OFF + 4194304;             // 8519680 B
    const size_t PART_OFF = NEED1;
    const size_t NEED2    = PART_OFF + (size_t)1024*4160*4;  // + 17039360 B

    if (ws_size >= NEED1) {
        unsigned short* xb = (unsigned short*)((char*)d_ws + XB_OFF);
        unsigned short* xt = (unsigned short*)((char*)d_ws + XT_OFF);
        prep_kernel <<<dim3(512),  dim3(256), 0, stream>>>(x, xb, xt);
        if (ws_size >= NEED2) {
            float* part = (float*)((char*)d_ws + PART_OFF);
            out_kernel5 <<<dim3(1024), dim3(256), 0, stream>>>(xb, xt, out, rho, part, 1);
            mean_kernel5<<<dim3(2048), dim3(256), 0, stream>>>(xb, rho, part, out, attn);
        } else {
            out_kernel5 <<<dim3(512),  dim3(256), 0, stream>>>(xb, xt, out, rho, nullptr, 0);
            mean_kernel5<<<dim3(2048), dim3(256), 0, stream>>>(xb, rho, nullptr, out, attn);
        }
    } else {
        fb_out_kernel <<<dim3(512),  dim3(256), 0, stream>>>(x, out, rho);
        fb_mean_kernel<<<dim3(1024), dim3(256), 0, stream>>>(x, rho, attn);
    }
}

// Round 14
// 75.769 us; speedup vs baseline: 1.0555x; 1.0555x over previous
//
#include <hip/hip_runtime.h>

// AttentionLayer: N=2, L=2048, D_MODEL=512, H=8, d=64
#define NBATCH 2
#define SEQ    2048
#define DMODEL 512
#define NH     8
#define HDIM   64
#define SCALE  0.125f   // 1/sqrt(64)

// exp base-2: 0.125 * log2(e)
#define K2 0.1803368801111204f

#if __has_builtin(__builtin_amdgcn_exp2f)
#define EXP2(x) __builtin_amdgcn_exp2f(x)
#else
#define EXP2(x) __expf((x) * 0.6931471805599453f)
#endif

typedef __attribute__((ext_vector_type(8)))  short bf16x8;   // MFMA A/B frag
typedef __attribute__((ext_vector_type(4)))  float f32x4;    // 16x16 C/D frag
typedef __attribute__((ext_vector_type(16))) float f32x16;   // 32x32 C/D frag

// fp32 -> bf16 round-to-nearest-even.
__device__ __forceinline__ unsigned short f2bf(float f) {
    union { float f; unsigned u; } v; v.f = f;
    unsigned r = v.u + 0x7FFFu + ((v.u >> 16) & 1u);
    return (unsigned short)(r >> 16);
}

__device__ __forceinline__ void pack4(unsigned short* dst, float4 v) {
    unsigned long long pk = (unsigned long long)f2bf(v.x)
        | ((unsigned long long)f2bf(v.y) << 16)
        | ((unsigned long long)f2bf(v.z) << 32)
        | ((unsigned long long)f2bf(v.w) << 48);
    __builtin_memcpy(dst, &pk, 8);   // alias-safe 8B LDS/global store
}

__device__ __forceinline__ bf16x8 pack8(float4 a, float4 b) {
    bf16x8 r;
    r[0]=(short)f2bf(a.x); r[1]=(short)f2bf(a.y); r[2]=(short)f2bf(a.z); r[3]=(short)f2bf(a.w);
    r[4]=(short)f2bf(b.x); r[5]=(short)f2bf(b.y); r[6]=(short)f2bf(b.z); r[7]=(short)f2bf(b.w);
    return r;
}

// pack two f32 -> one dword of 2 bf16 (RNE), low word = s0. REGISTER-ONLY use.
__device__ __forceinline__ unsigned cvt_pk_bf16(float s0, float s1) {
    unsigned d;
    asm("v_cvt_pk_bf16_f32 %0, %1, %2" : "=v"(d) : "v"(s0), "v"(s1));
    return d;
}

// async 16B global->LDS DMA; lds dest is wave-uniform base + lane*16;
// swizzling is done on the GLOBAL source address (rule #21).
__device__ __forceinline__ void gld_lds16(const unsigned short* g, unsigned short* l) {
    __builtin_amdgcn_global_load_lds(
        (const __attribute__((address_space(1))) unsigned int*)(const void*)g,
        (__attribute__((address_space(3))) unsigned int*)(void*)l, 16, 0, 0);
}

// ---------------------------------------------------------------------------
// Prep: xb = bf16(x) row-major [n][l][512]; xt = bf16(x) transposed per head
// [n][h][64][2048]. Grid: n x h x (SEQ/64) = 512 blocks. Reads x once.
// ---------------------------------------------------------------------------
__global__ __launch_bounds__(256) void prep_kernel(const float* __restrict__ x,
                                                   unsigned short* __restrict__ xb,
                                                   unsigned short* __restrict__ xt) {
    __shared__ unsigned short Tb[64][72];   // 9216 B, padded
    const int bid = blockIdx.x;
    const int n = bid >> 8, h = (bid >> 5) & 7, st = bid & 31;
    const int s0 = st * 64;
    const int t = threadIdx.x;
    {
        const int s = t >> 2, d0 = (t & 3) * 16;
        const float* xp = x + ((size_t)(n*SEQ + s0 + s))*DMODEL + h*HDIM + d0;
        #pragma unroll
        for (int i = 0; i < 4; ++i) pack4(&Tb[s][d0 + 4*i], *(const float4*)(xp + 4*i));
    }
    __syncthreads();
    {   // xb slice write (row-major, 32B/thread)
        const int s = t >> 2, d0 = (t & 3) * 16;
        unsigned short* bp = xb + ((size_t)(n*SEQ + s0 + s))*DMODEL + h*HDIM + d0;
        *(bf16x8*)bp       = *(const bf16x8*)&Tb[s][d0];
        *(bf16x8*)(bp + 8) = *(const bf16x8*)&Tb[s][d0 + 8];
    }
    {   // xt slice write (transposed, 32B/thread)
        const int d = t >> 2, c0 = (t & 3) * 16;
        bf16x8 v0, v1;
        #pragma unroll
        for (int j = 0; j < 8; ++j) {
            v0[j] = (short)Tb[c0 + j][d];
            v1[j] = (short)Tb[c0 + 8 + j][d];
        }
        unsigned short* tp = xt + ((size_t)((n*NH + h)*HDIM + d))*SEQ + s0 + c0;
        *(bf16x8*)tp       = v0;
        *(bf16x8*)(tp + 8) = v1;
    }
}

// ---------------------------------------------------------------------------
// Kernel A (v5): 32x32x16 MFMA, in-register P, LDS-traffic-minimized.
// (unchanged from round 12 — passed at absmax 0.03125)
// ---------------------------------------------------------------------------
__global__ __launch_bounds__(256, 4) void out_kernel5(const unsigned short* __restrict__ xb,
                                                      const unsigned short* __restrict__ xt,
                                                      float* __restrict__ out,
                                                      float* __restrict__ rho,
                                                      float* __restrict__ part,
                                                      int split) {
    __shared__ unsigned short Kb[2][64*64];   // 16384 B, swizzled linear
    __shared__ unsigned short Vt[2][64*64];   // 16384 B, swizzled linear

    const int i   = blockIdx.x;
    const int cps = gridDim.x >> 3;            // 64 (512) or 128 (1024)
    const int bid = (i & 7) * cps + (i >> 3);  // bijective XCD-chunked swizzle
    int n, h, lt, ss;
    if (split) { n = bid >> 9; h = (bid >> 6) & 7; lt = (bid >> 1) & 31; ss = bid & 1; }
    else       { n = bid >> 8; h = (bid >> 5) & 7; lt = bid & 31;        ss = 0;       }
    const int l0 = lt * 64;
    const int sbase = ss << 10;
    const int nch = split ? 16 : 32;

    const int tid = threadIdx.x;
    const int wv = tid >> 6, lane = tid & 63;
    const int lrow = lane & 31;               // 32-wide lane row/col index
    const int hi = lane >> 5;                 // lane half
    const int qh = wv & 1, sh = wv >> 1;      // wave roles

    // Q frags in registers: B-frag (col=lane&31=q, k=(lane>>5)*8+j), 4 k-steps
    const unsigned short* qg = xb + ((size_t)(n*SEQ + l0 + qh*32 + lrow))*DMODEL + h*HDIM;
    bf16x8 qf[4];
    #pragma unroll
    for (int kst = 0; kst < 4; ++kst)
        qf[kst] = *(const bf16x8*)(qg + kst*16 + hi*8);

    const int srow8  = wv*8 + (lane >> 3);    // staging row (all 4 waves)
    const int schunk = lane & 7;
    const unsigned short* kbase = xb + (size_t)(n*SEQ)*DMODEL + h*HDIM;
    const unsigned short* vbase = xt + ((size_t)(n*NH + h)*HDIM)*SEQ;

    auto stage = [&](int buf, int s0) {
        #pragma unroll
        for (int it = 0; it < 2; ++it) {
            const int row = it*32 + srow8;
            const int gc  = schunk ^ (row & 7);
            gld_lds16(kbase + (size_t)(s0 + row)*DMODEL + gc*8,
                      &Kb[buf][it*2048 + wv*512]);
        }
        #pragma unroll
        for (int it = 0; it < 2; ++it) {
            const int d  = it*32 + srow8;
            const int gc = schunk ^ (d & 7);
            gld_lds16(vbase + (size_t)d*SEQ + s0 + gc*8,
                      &Vt[buf][it*2048 + wv*512]);
        }
    };

    f32x16 ovA = {0.f}, ovB = {0.f};   // O partial: d-tile 0 / 1, col q
    #pragma unroll
    for (int r = 0; r < 16; ++r) { ovA[r] = 0.f; ovB[r] = 0.f; }
    float rs = 0.f;                    // row-sum partial (this lane's e's)

    stage(0, sbase);
    __syncthreads();
    int cur = 0;

    for (int c = 0; c < nch; ++c) {
        if (c < nch - 1) stage(cur ^ 1, sbase + (c + 1) * 64);   // prefetch

        // ---- QK^T (swapped): D[s][q], s-tile = sh half of chunk ----
        f32x16 acc;
        #pragma unroll
        for (int r = 0; r < 16; ++r) acc[r] = 0.f;
        #pragma unroll
        for (int kst = 0; kst < 4; ++kst) {
            const int g = ((kst*2 + hi) ^ (lrow & 7)) << 3;   // inverse swizzle
            const bf16x8 kf = *(const bf16x8*)&Kb[cur][(sh*32 + lrow)*64 + g];
            acc = __builtin_amdgcn_mfma_f32_32x32x16_bf16(kf, qf[kst], acc, 0, 0, 0);
        }
        // ---- exp (in place) + row-sum ----
        #pragma unroll
        for (int r = 0; r < 16; ++r) {
            acc[r] = EXP2(acc[r] * K2);
            rs += acc[r];
        }
        // ---- PV: two 16-s steps; P assembled in-register ----
        #pragma unroll
        for (int p = 0; p < 2; ++p) {
            const unsigned g0 = cvt_pk_bf16(acc[8*p+0], acc[8*p+1]);
            const unsigned g1 = cvt_pk_bf16(acc[8*p+2], acc[8*p+3]);
            const unsigned g2 = cvt_pk_bf16(acc[8*p+4], acc[8*p+5]);
            const unsigned g3 = cvt_pk_bf16(acc[8*p+6], acc[8*p+7]);
            const unsigned b0 = hi ? g0 : g2;
            const unsigned b1 = hi ? g1 : g3;
            const unsigned r0 = (unsigned)__shfl_xor((int)b0, 32);
            const unsigned r1 = (unsigned)__shfl_xor((int)b1, 32);
            union { unsigned u[4]; bf16x8 h8; } pf;
            pf.u[0] = hi ? r0 : g0;
            pf.u[1] = hi ? r1 : g1;
            pf.u[2] = hi ? g2 : r0;
            pf.u[3] = hi ? g3 : r1;
            const int gv = ((sh*4 + p*2 + hi) ^ (lrow & 7)) << 3;
            const bf16x8 v0 = *(const bf16x8*)&Vt[cur][( 0 + lrow)*64 + gv];
            const bf16x8 v1 = *(const bf16x8*)&Vt[cur][(32 + lrow)*64 + gv];
            ovA = __builtin_amdgcn_mfma_f32_32x32x16_bf16(v0, pf.h8, ovA, 0, 0, 0);
            ovB = __builtin_amdgcn_mfma_f32_32x32x16_bf16(v1, pf.h8, ovB, 0, 0, 0);
        }
        __syncthreads();   // next buffer staged + all reads of cur done
        cur ^= 1;
    }

    // ---- cross-sh reduction (O and rs) via reused LDS ----
    rs += __shfl_xor(rs, 32);                  // sum over lane halves (same q)
    float* red = (float*)&Vt[0][0];            // 16 KB: [qh][q32][d]
    float* rsr = (float*)&Kb[0][0];            // 256 B: [qh*32+q32]
    if (sh == 1) {
        #pragma unroll
        for (int g = 0; g < 4; ++g) {
            float4 a = { ovA[4*g+0], ovA[4*g+1], ovA[4*g+2], ovA[4*g+3] };
            float4 b = { ovB[4*g+0], ovB[4*g+1], ovB[4*g+2], ovB[4*g+3] };
            *(float4*)&red[qh*2048 + lrow*64 +  0 + g*8 + 4*hi] = a;
            *(float4*)&red[qh*2048 + lrow*64 + 32 + g*8 + 4*hi] = b;
        }
        if (hi == 0) rsr[qh*32 + lrow] = rs;
    }
    __syncthreads();
    if (sh == 0) {
        const float rs_tot = rs + rsr[qh*32 + lrow];
        #pragma unroll
        for (int g = 0; g < 4; ++g) {
            float4 a = *(const float4*)&red[qh*2048 + lrow*64 +  0 + g*8 + 4*hi];
            float4 b = *(const float4*)&red[qh*2048 + lrow*64 + 32 + g*8 + 4*hi];
            ovA[4*g+0]+=a.x; ovA[4*g+1]+=a.y; ovA[4*g+2]+=a.z; ovA[4*g+3]+=a.w;
            ovB[4*g+0]+=b.x; ovB[4*g+1]+=b.y; ovB[4*g+2]+=b.z; ovB[4*g+3]+=b.w;
        }
        const int qloc = qh*32 + lrow;
        if (split) {
            float* pp = part + ((size_t)(((n*NH + h)*32 + lt)*2 + ss))*4160;
            #pragma unroll
            for (int g = 0; g < 4; ++g) {
                float4 a = { ovA[4*g+0], ovA[4*g+1], ovA[4*g+2], ovA[4*g+3] };
                float4 b = { ovB[4*g+0], ovB[4*g+1], ovB[4*g+2], ovB[4*g+3] };
                *(float4*)&pp[qloc*64 +  0 + g*8 + 4*hi] = a;
                *(float4*)&pp[qloc*64 + 32 + g*8 + 4*hi] = b;
            }
            if (hi == 0) pp[4096 + qloc] = rs_tot;
        } else {
            const float iv = 1.f / rs_tot;
            float* op = out + ((size_t)(n*SEQ + l0 + qloc))*DMODEL + h*HDIM;
            #pragma unroll
            for (int g = 0; g < 4; ++g) {
                float4 a = { ovA[4*g+0]*iv, ovA[4*g+1]*iv, ovA[4*g+2]*iv, ovA[4*g+3]*iv };
                float4 b = { ovB[4*g+0]*iv, ovB[4*g+1]*iv, ovB[4*g+2]*iv, ovB[4*g+3]*iv };
                *(float4*)&op[ 0 + g*8 + 4*hi] = a;
                *(float4*)&op[32 + g*8 + 4*hi] = b;
            }
            if (hi == 0) rho[(size_t)(n*NH + h)*SEQ + l0 + qloc] = rs_tot;
        }
    }
}

// ---------------------------------------------------------------------------
// Kernel B (v6): round-12's proven mean_kernel4 (Q+K DMA staged, 2-phase head
// pipeline, 34.8 KB LDS) + ABSORBED COMBINE: in the split path, blocks with
// st<8 also write out[] for (n, h=st, lt) from part, and invb is computed
// from part sums (separate combine_kernel launch eliminated).
// Grid 2048 XCD-swizzled, 4 waves.
// ---------------------------------------------------------------------------
__global__ __launch_bounds__(256) void mean_kernel6(const unsigned short* __restrict__ xb,
                                                    const float* __restrict__ rho,
                                                    const float* __restrict__ part,
                                                    float* __restrict__ out,
                                                    float* __restrict__ attn) {
    __shared__ unsigned short Qb[2][64*64];   // 2 x 8 KB
    __shared__ unsigned short Kb[2][64*64];   // 2 x 8 KB
    __shared__ float invb[NH][64];            // 2 KB

    const int i   = blockIdx.x;
    const int bid = (i & 7) * 256 + (i >> 3);  // bijective (2048 = 8*256)
    const int n = bid >> 10, lt = (bid >> 5) & 31, st = bid & 31;
    const int l0 = lt * 64, s0 = st * 64;
    const int tid = threadIdx.x;
    const int wv = tid >> 6, lane = tid & 63;
    const int lr = lane & 15, lg = lane >> 4;

    const int srow8  = wv*8 + (lane >> 3);
    const int schunk = lane & 7;

    auto stage = [&](int buf, int h) {
        #pragma unroll
        for (int it = 0; it < 2; ++it) {   // Q tile: 64 rows x 128B
            const int row = it*32 + srow8;
            const int gc  = schunk ^ (row & 7);
            gld_lds16(xb + ((size_t)(n*SEQ + l0 + row))*DMODEL + h*HDIM + gc*8,
                      &Qb[buf][it*2048 + wv*512]);
        }
        #pragma unroll
        for (int it = 0; it < 2; ++it) {   // K tile: 64 rows x 128B
            const int row = it*32 + srow8;
            const int gc  = schunk ^ (row & 7);
            gld_lds16(xb + ((size_t)(n*SEQ + s0 + row))*DMODEL + h*HDIM + gc*8,
                      &Kb[buf][it*2048 + wv*512]);
        }
    };

    stage(0, 0);                              // issue first Q+K DMA ASAP

    // absorbed combine: blocks st<8 write out[] for (n, h=st, lt)
    if (part != nullptr && st < NH) {
        const int hC = st;
        const float* p0 = part + ((size_t)(((n*NH + hC)*32 + lt)*2))*4160;
        const float* p1 = p0 + 4160;
        const int q = tid >> 2, dg = (tid & 3) * 16;
        const float rsT = p0[4096 + q] + p1[4096 + q];
        const float iv = 1.f / rsT;
        float* op = out + ((size_t)(n*SEQ + l0 + q))*DMODEL + hC*HDIM + dg;
        #pragma unroll
        for (int k = 0; k < 4; ++k) {
            float4 a = *(const float4*)&p0[q*64 + dg + 4*k];
            float4 b = *(const float4*)&p1[q*64 + dg + 4*k];
            float4 o = { (a.x+b.x)*iv, (a.y+b.y)*iv, (a.z+b.z)*iv, (a.w+b.w)*iv };
            *(float4*)&op[4*k] = o;
        }
    }

    // invb: 0.125/rho per (head, row); rho from part sums in split path
    for (int j = tid; j < NH*64; j += 256) {
        const int hh = j >> 6, row = j & 63;
        float rv;
        if (part != nullptr) {
            const float* pb_ = part + ((size_t)(((n*NH + hh)*32 + lt)*2))*4160 + 4096;
            rv = pb_[row] + pb_[4160 + row];
        } else {
            rv = rho[(size_t)(n*NH + hh)*SEQ + l0 + row];
        }
        invb[hh][row] = 0.125f / rv;
    }

    float mean[4][4];
    #pragma unroll
    for (int ct = 0; ct < 4; ++ct)
        #pragma unroll
        for (int r = 0; r < 4; ++r) mean[ct][r] = 0.f;

    __syncthreads();                       // covers invb writes + DMA drain
    int cur = 0;

    for (int h = 0; h < NH; ++h) {
        if (h < NH-1) stage(cur ^ 1, h + 1);

        const int qrow = wv*16 + lr;
        const int c0 = (lg ^ (lr & 7)) << 3;
        const bf16x8 a0 = *(const bf16x8*)&Qb[cur][qrow*64 + c0];
        const bf16x8 a1 = *(const bf16x8*)&Qb[cur][qrow*64 + (c0 ^ 32)];
        const float logiv = __log2f(invb[h][qrow]);
        #pragma unroll
        for (int ct = 0; ct < 4; ++ct) {
            const unsigned short* kr = &Kb[cur][(ct*16 + lr)*64];
            bf16x8 b0 = *(const bf16x8*)&kr[c0];
            bf16x8 b1 = *(const bf16x8*)&kr[c0 ^ 32];
            f32x4 acc = {0.f,0.f,0.f,0.f};
            acc = __builtin_amdgcn_mfma_f32_16x16x32_bf16(b0, a0, acc, 0,0,0);
            acc = __builtin_amdgcn_mfma_f32_16x16x32_bf16(b1, a1, acc, 0,0,0);
            #pragma unroll
            for (int r = 0; r < 4; ++r)
                mean[ct][r] += EXP2(fmaf(acc[r], K2, logiv));
        }
        __syncthreads();
        cur ^= 1;
    }

    // epilogue: per lane 4 consecutive s per ct -> float4 stores
    const int arow = n*SEQ + l0 + wv*16 + lr;
    #pragma unroll
    for (int ct = 0; ct < 4; ++ct) {
        float4 v = { mean[ct][0], mean[ct][1], mean[ct][2], mean[ct][3] };
        *(float4*)&attn[(size_t)arow*SEQ + s0 + ct*16 + lg*4] = v;
    }
}

// ============================ fallback path ================================
// (round-3 kernels, used only if ws_size can't hold xb+xt; known-correct)
__global__ __launch_bounds__(256) void fb_out_kernel(const float* __restrict__ x,
                                                     float* __restrict__ out,
                                                     float* __restrict__ rho) {
    __shared__ unsigned short Kbuf[128][72];
    __shared__ unsigned short vT[64][136];
    __shared__ unsigned short pbuf[64][136];
    const int bid = blockIdx.x;
    const int n  = bid >> 8, h = (bid >> 5) & 7, lt = bid & 31;
    const int l0 = lt * 64;
    const int tid = threadIdx.x;
    const int wv  = tid >> 6, lane = tid & 63;
    const int lr  = lane & 15, lg = lane >> 4;
    const float* qp = x + ((size_t)(n*SEQ + l0 + wv*16 + lr))*DMODEL + h*HDIM + lg*8;
    const bf16x8 a0 = pack8(*(const float4*)qp,      *(const float4*)(qp+4));
    const bf16x8 a1 = pack8(*(const float4*)(qp+32), *(const float4*)(qp+36));
    f32x4 ov0 = {0.f,0.f,0.f,0.f}, ov1 = {0.f,0.f,0.f,0.f};
    f32x4 ov2 = {0.f,0.f,0.f,0.f}, ov3 = {0.f,0.f,0.f,0.f};
    float rs[4] = {0.f,0.f,0.f,0.f};
    for (int s0 = 0; s0 < SEQ; s0 += 128) {
        __syncthreads();
        {
            const int srow = tid >> 1, dbase = (tid & 1) * 32;
            const float* kp = x + ((size_t)(n*SEQ + s0 + srow))*DMODEL + h*HDIM + dbase;
            #pragma unroll
            for (int i = 0; i < 8; ++i) {
                float4 v = *(const float4*)(kp + 4*i);
                pack4(&Kbuf[srow][dbase + 4*i], v);
                const int d = dbase + 4*i;
                vT[d+0][srow] = f2bf(v.x); vT[d+1][srow] = f2bf(v.y);
                vT[d+2][srow] = f2bf(v.z); vT[d+3][srow] = f2bf(v.w);
            }
        }
        __syncthreads();
        #pragma unroll
        for (int ct = 0; ct < 8; ++ct) {
            const unsigned short* bp = &Kbuf[ct*16 + lr][lg*8];
            bf16x8 b0 = *(const bf16x8*)bp;
            bf16x8 b1 = *(const bf16x8*)(bp + 32);
            f32x4 acc = {0.f,0.f,0.f,0.f};
            acc = __builtin_amdgcn_mfma_f32_16x16x32_bf16(a0, b0, acc, 0,0,0);
            acc = __builtin_amdgcn_mfma_f32_16x16x32_bf16(a1, b1, acc, 0,0,0);
            #pragma unroll
            for (int r = 0; r < 4; ++r) {
                const float e = __expf(acc[r] * SCALE);
                rs[r] += e;
                pbuf[wv*16 + lg*4 + r][ct*16 + lr] = f2bf(e);
            }
        }
        __syncthreads();
        #pragma unroll
        for (int ks = 0; ks < 4; ++ks) {
            bf16x8 pa = *(const bf16x8*)&pbuf[wv*16 + lr][ks*32 + lg*8];
            bf16x8 v0 = *(const bf16x8*)&vT[ 0 + lr][ks*32 + lg*8];
            bf16x8 v1 = *(const bf16x8*)&vT[16 + lr][ks*32 + lg*8];
            bf16x8 v2 = *(const bf16x8*)&vT[32 + lr][ks*32 + lg*8];
            bf16x8 v3 = *(const bf16x8*)&vT[48 + lr][ks*32 + lg*8];
            ov0 = __builtin_amdgcn_mfma_f32_16x16x32_bf16(pa, v0, ov0, 0,0,0);
            ov1 = __builtin_amdgcn_mfma_f32_16x16x32_bf16(pa, v1, ov1, 0,0,0);
            ov2 = __builtin_amdgcn_mfma_f32_16x16x32_bf16(pa, v2, ov2, 0,0,0);
            ov3 = __builtin_amdgcn_mfma_f32_16x16x32_bf16(pa, v3, ov3, 0,0,0);
        }
    }
    #pragma unroll
    for (int r = 0; r < 4; ++r) {
        float s = rs[r];
        s += __shfl_xor(s, 1, 16); s += __shfl_xor(s, 2, 16);
        s += __shfl_xor(s, 4, 16); s += __shfl_xor(s, 8, 16);
        rs[r] = s;
    }
    const int row0 = l0 + wv*16 + lg*4;
    if (lr == 0) {
        #pragma unroll
        for (int r = 0; r < 4; ++r)
            rho[(size_t)(n*NH + h)*SEQ + row0 + r] = rs[r];
    }
    #pragma unroll
    for (int r = 0; r < 4; ++r) {
        const float iv = 1.f / rs[r];
        float* op = out + ((size_t)(n*SEQ + row0 + r))*DMODEL + h*HDIM + lr;
        op[0] = ov0[r]*iv; op[16] = ov1[r]*iv; op[32] = ov2[r]*iv; op[48] = ov3[r]*iv;
    }
}

__global__ __launch_bounds__(256) void fb_mean_kernel(const float* __restrict__ x,
                                                      const float* __restrict__ rho,
                                                      float* __restrict__ attn) {
    __shared__ unsigned short Qb[64][72];
    __shared__ unsigned short Kb[128][72];
    __shared__ float          invb[64];
    const int bid = blockIdx.x;
    const int n  = bid >> 9, lt = (bid >> 4) & 31, st = bid & 15;
    const int l0 = lt * 64, s0 = st * 128;
    const int tid = threadIdx.x;
    const int wv  = tid >> 6, lane = tid & 63;
    const int lr  = lane & 15, lg = lane >> 4;
    float mean[8][4];
    #pragma unroll
    for (int ct = 0; ct < 8; ++ct)
        #pragma unroll
        for (int r = 0; r < 4; ++r) mean[ct][r] = 0.f;
    for (int h = 0; h < NH; ++h) {
        __syncthreads();
        {
            const int qrow = tid >> 2, qd = (tid & 3) * 16;
            const float* qp = x + ((size_t)(n*SEQ + l0 + qrow))*DMODEL + h*HDIM + qd;
            #pragma unroll
            for (int i = 0; i < 4; ++i)
                pack4(&Qb[qrow][qd + 4*i], *(const float4*)(qp + 4*i));
        }
        {
            const int srow = tid >> 1, dbase = (tid & 1) * 32;
            const float* kp = x + ((size_t)(n*SEQ + s0 + srow))*DMODEL + h*HDIM + dbase;
            #pragma unroll
            for (int i = 0; i < 8; ++i)
                pack4(&Kb[srow][dbase + 4*i], *(const float4*)(kp + 4*i));
        }
        if (tid < 64)
            invb[tid] = 0.125f / rho[(size_t)(n*NH + h)*SEQ + l0 + tid];
        __syncthreads();
        const unsigned short* ap = &Qb[wv*16 + lr][lg*8];
        const bf16x8 a0 = *(const bf16x8*)ap;
        const bf16x8 a1 = *(const bf16x8*)(ap + 32);
        #pragma unroll
        for (int ct = 0; ct < 8; ++ct) {
            const unsigned short* bp = &Kb[ct*16 + lr][lg*8];
            bf16x8 b0 = *(const bf16x8*)bp;
            bf16x8 b1 = *(const bf16x8*)(bp + 32);
            f32x4 acc = {0.f,0.f,0.f,0.f};
            acc = __builtin_amdgcn_mfma_f32_16x16x32_bf16(a0, b0, acc, 0,0,0);
            acc = __builtin_amdgcn_mfma_f32_16x16x32_bf16(a1, b1, acc, 0,0,0);
            #pragma unroll
            for (int r = 0; r < 4; ++r)
                mean[ct][r] += __expf(acc[r] * SCALE) * invb[wv*16 + lg*4 + r];
        }
    }
    #pragma unroll
    for (int ct = 0; ct < 8; ++ct)
        #pragma unroll
        for (int r = 0; r < 4; ++r)
            attn[((size_t)(n*SEQ + l0 + wv*16 + lg*4 + r))*SEQ + s0 + ct*16 + lr]
                = mean[ct][r];
}

extern "C" void kernel_launch(void* const* d_in, const int* in_sizes, int n_in,
                              void* d_out, int out_size, void* d_ws, size_t ws_size,
                              hipStream_t stream) {
    (void)in_sizes; (void)n_in; (void)out_size;
    const float* x = (const float*)d_in[0];
    float* out  = (float*)d_out;                          // [2][2048][512]
    float* attn = out + (size_t)NBATCH*SEQ*DMODEL;        // [2][2048][2048]
    float* rho  = (float*)d_ws;                           // 128 KiB

    const size_t XB_OFF   = 131072;                       // 4 MiB bf16 copy
    const size_t XT_OFF   = XB_OFF + 4194304;             // 4 MiB bf16 transpose
    const size_t NEED1    = XT_OFF + 4194304;             // 8519680 B
    const size_t PART_OFF = NEED1;
    const size_t NEED2    = PART_OFF + (size_t)1024*4160*4;  // + 17039360 B

    if (ws_size >= NEED1) {
        unsigned short* xb = (unsigned short*)((char*)d_ws + XB_OFF);
        unsigned short* xt = (unsigned short*)((char*)d_ws + XT_OFF);
        prep_kernel <<<dim3(512),  dim3(256), 0, stream>>>(x, xb, xt);
        if (ws_size >= NEED2) {
            float* part = (float*)((char*)d_ws + PART_OFF);
            out_kernel5 <<<dim3(1024), dim3(256), 0, stream>>>(xb, xt, out, rho, part, 1);
            mean_kernel6<<<dim3(2048), dim3(256), 0, stream>>>(xb, rho, part, out, attn);
        } else {
            out_kernel5 <<<dim3(512),  dim3(256), 0, stream>>>(xb, xt, out, rho, nullptr, 0);
            mean_kernel6<<<dim3(2048), dim3(256), 0, stream>>>(xb, rho, nullptr, out, attn);
        }
    } else {
        fb_out_kernel <<<dim3(512),  dim3(256), 0, stream>>>(x, out, rho);
        fb_mean_kernel<<<dim3(1024), dim3(256), 0, stream>>>(x, rho, attn);
    }
}